// Round 7
// baseline (632.333 us; speedup 1.0000x reference)
//
#include <hip/hip_runtime.h>

// MGU forward, swapped-orientation split-bf16 MFMA. B=131072, TAU=20, HID=64.
// Block = 64 rows, 4 waves; wave owns 16 rows (r = lane&15), ALL 64 units.
// GEMM computes PRE^T = W * S : A = W (static, LDS, fragment-ordered with
// column permutation sigma), B = state (built IN REGISTERS from the lane's
// own previous D-fragment values -- sigma makes the B-frag slot map lane-local:
//   sigma(32s + 8q + i) = 16*(2s + (i>>2)) + 4q + (i&3)
// so slot i' of kstep s at lane (q,r) = S_{T=2s+(i'>>2)}[i'&3], which is this
// lane's D/epilogue register). Zero cross-lane ops, zero LDS writes, zero
// bank conflicts in the recurrence.
// Bias + x-term: one aug-MFMA per tile/gate, A-slots [fxhi,fxlo,fxhi,fbhi,fblo],
// B-slots [xhi,xhi,xlo,1,1] (lanes q>0 read a zero chunk) -> full precision.
// 3-term split everywhere: hi*hi + lo*hi + hi*lo (drop lo*lo ~2^-17).
// Fragment maps (m89-verified, R5-validated end-to-end):
//   A: lane L holds A[m=L&15][k=(L>>4)*8+i] ; B: lane L holds B[k=(L>>4)*8+i][n=L&15]
//   C/D: lane L reg i holds D[m=(L>>4)*4+i][n=L&15]

constexpr int BATCH = 131072;
constexpr int TAU   = 20;
constexpr int HID   = 64;
constexpr int FAN   = 65;
constexpr int NT    = 256;
constexpr int ROWS  = 64;

typedef float    f32x4 __attribute__((ext_vector_type(4)));
typedef short    s16x8 __attribute__((ext_vector_type(8)));
typedef unsigned u32x4 __attribute__((ext_vector_type(4)));

static __device__ __forceinline__ short bf16_rne(float f) {
    unsigned u = __builtin_bit_cast(unsigned, f);
    return (short)((u + 0x7FFFu + ((u >> 16) & 1u)) >> 16);
}
static __device__ __forceinline__ float bf16_up(short s) {
    return __builtin_bit_cast(float, ((unsigned)(unsigned short)s) << 16);
}
static __device__ __forceinline__ float fast_sigmoid(float a) {
    return __builtin_amdgcn_rcpf(1.0f + __expf(-a));
}
static __device__ __forceinline__ float fast_tanh(float a) {
    return 1.0f - 2.0f * __builtin_amdgcn_rcpf(1.0f + __expf(2.0f * a));
}
// pack trunc-bf16(a) into low short, trunc-bf16(b) into high short
static __device__ __forceinline__ unsigned pk2(float a, float b) {
    return (__builtin_bit_cast(unsigned, a) >> 16) |
           (__builtin_bit_cast(unsigned, b) & 0xFFFF0000u);
}
static __device__ __forceinline__ float trunc_hi(float v) {
    return __builtin_bit_cast(float, __builtin_bit_cast(unsigned, v) & 0xFFFF0000u);
}

#define MFMA(A, B, C) __builtin_amdgcn_mfma_f32_16x16x32_bf16((A), (B), (C), 0, 0, 0)

// W fragment chunk base (shorts): (g*8 + T*2 + s)*1024 + p*512 + L*8
#define WOFF(g, T, s) (((g) * 8 + (T) * 2 + (s)) * 1024)

// build hi/lo B-frags for both ksteps from state quads (all lane-local)
#define BUILD_B(SA, SB, SC, SD, BH0v, BL0v, BH1v, BL1v) { \
    const float lA0 = SA[0] - trunc_hi(SA[0]), lA1 = SA[1] - trunc_hi(SA[1]); \
    const float lA2 = SA[2] - trunc_hi(SA[2]), lA3 = SA[3] - trunc_hi(SA[3]); \
    const float lB0 = SB[0] - trunc_hi(SB[0]), lB1 = SB[1] - trunc_hi(SB[1]); \
    const float lB2 = SB[2] - trunc_hi(SB[2]), lB3 = SB[3] - trunc_hi(SB[3]); \
    const float lC0 = SC[0] - trunc_hi(SC[0]), lC1 = SC[1] - trunc_hi(SC[1]); \
    const float lC2 = SC[2] - trunc_hi(SC[2]), lC3 = SC[3] - trunc_hi(SC[3]); \
    const float lD0 = SD[0] - trunc_hi(SD[0]), lD1 = SD[1] - trunc_hi(SD[1]); \
    const float lD2 = SD[2] - trunc_hi(SD[2]), lD3 = SD[3] - trunc_hi(SD[3]); \
    BH0v = __builtin_bit_cast(s16x8, (u32x4){pk2(SA[0],SA[1]), pk2(SA[2],SA[3]), pk2(SB[0],SB[1]), pk2(SB[2],SB[3])}); \
    BL0v = __builtin_bit_cast(s16x8, (u32x4){pk2(lA0,lA1),     pk2(lA2,lA3),     pk2(lB0,lB1),     pk2(lB2,lB3)}); \
    BH1v = __builtin_bit_cast(s16x8, (u32x4){pk2(SC[0],SC[1]), pk2(SC[2],SC[3]), pk2(SD[0],SD[1]), pk2(SD[2],SD[3])}); \
    BL1v = __builtin_bit_cast(s16x8, (u32x4){pk2(lC0,lC1),     pk2(lC2,lC3),     pk2(lD0,lD1),     pk2(lD2,lD3)}); }

// 3-term split accumulation for one (tile, kstep)
#define KMFMA(g, T, s, BH, BL, C) { \
    const s16x8 ah_ = *(const s16x8*)&sW[WOFF(g, T, s) + Lx8]; \
    const s16x8 al_ = *(const s16x8*)&sW[WOFF(g, T, s) + 512 + Lx8]; \
    C = MFMA(ah_, BH, C); C = MFMA(al_, BH, C); C = MFMA(ah_, BL, C); }

// full gate: aug init + 2 ksteps x 4 tiles
#define GATE(g, BH0v, BL0v, BH1v, BL1v, C0, C1, C2, C3) { \
    const f32x4 z_ = {0.f, 0.f, 0.f, 0.f}; \
    C0 = MFMA(*(const s16x8*)&augBase[((g) * 4 + 0) * augStep], augB, z_); \
    C1 = MFMA(*(const s16x8*)&augBase[((g) * 4 + 1) * augStep], augB, z_); \
    C2 = MFMA(*(const s16x8*)&augBase[((g) * 4 + 2) * augStep], augB, z_); \
    C3 = MFMA(*(const s16x8*)&augBase[((g) * 4 + 3) * augStep], augB, z_); \
    KMFMA(g, 0, 0, BH0v, BL0v, C0) KMFMA(g, 1, 0, BH0v, BL0v, C1) \
    KMFMA(g, 2, 0, BH0v, BL0v, C2) KMFMA(g, 3, 0, BH0v, BL0v, C3) \
    KMFMA(g, 0, 1, BH1v, BL1v, C0) KMFMA(g, 1, 1, BH1v, BL1v, C1) \
    KMFMA(g, 2, 1, BH1v, BL1v, C2) KMFMA(g, 3, 1, BH1v, BL1v, C3) }

#define SIG4(F, C) { F[0] = fast_sigmoid(C[0]); F[1] = fast_sigmoid(C[1]); \
                     F[2] = fast_sigmoid(C[2]); F[3] = fast_sigmoid(C[3]); }
#define UPD4(S, F, C, P) { S[0] = fmaf(F[0], fast_tanh(C[0]), P[0]); \
                           S[1] = fmaf(F[1], fast_tanh(C[1]), P[1]); \
                           S[2] = fmaf(F[2], fast_tanh(C[2]), P[2]); \
                           S[3] = fmaf(F[3], fast_tanh(C[3]), P[3]); }

__global__ __launch_bounds__(NT, 4) void mgu_fwd(
    const float* __restrict__ x,    // [B, TAU]
    const float* __restrict__ h0,   // [B, HID]
    const float* __restrict__ Wf,   // [HID, FAN]
    const float* __restrict__ bfv,  // [HID]
    const float* __restrict__ Wc,   // [HID, FAN]
    const float* __restrict__ bcv,  // [HID]
    const float* __restrict__ Wo,   // [1, HID]
    const float* __restrict__ bov,  // [1]
    float* __restrict__ out)        // [B, 1]
{
    __shared__ short sW[16384];        // W frags: (g*8+T*2+s)*1024 + p*512 + L*8 + i
    __shared__ short sAug[1032];       // aug frags (g*4+T)*128 + m*8 + i ; [1024..1031]=0
    __shared__ float sX[ROWS * TAU];   // x tile, [local row][t]
    __shared__ float sWo[HID];

    const int tid = threadIdx.x;
    const long rb0 = (long)blockIdx.x * ROWS;

    // ---- one-time: W -> sigma-permuted, fragment-ordered hi/lo planes
    for (int idx = tid; idx < 8192; idx += NT) {
        const int i = idx & 7, Li = (idx >> 3) & 63, s = (idx >> 9) & 1,
                  T = (idx >> 10) & 3, g = (idx >> 12) & 1;
        const int u = 16 * (2 * s + (i >> 2)) + 4 * (Li >> 4) + (i & 3); // sigma
        const float* Wg = g ? Wc : Wf;
        const float wv = Wg[(16 * T + (Li & 15)) * FAN + 1 + u];
        const short hi = bf16_rne(wv);
        const int base = (g * 8 + T * 2 + s) * 1024 + Li * 8 + i;
        sW[base] = hi;
        sW[base + 512] = bf16_rne(wv - bf16_up(hi));
    }
    // ---- one-time: aug A-frags (bias + x-column), lanes m=0..15 only
    for (int idx = tid; idx < 128; idx += NT) {
        const int m = idx & 15, T = (idx >> 4) & 3, g = (idx >> 6) & 1;
        const float* Wg = g ? Wc : Wf;
        const float* bg = g ? bcv : bfv;
        const float fx = Wg[(16 * T + m) * FAN];
        const float fb = bg[16 * T + m];
        const short fxh = bf16_rne(fx), fbh = bf16_rne(fb);
        short* c = &sAug[(g * 4 + T) * 128 + m * 8];
        c[0] = fxh; c[1] = bf16_rne(fx - bf16_up(fxh)); c[2] = fxh;
        c[3] = fbh; c[4] = bf16_rne(fb - bf16_up(fbh));
        c[5] = 0; c[6] = 0; c[7] = 0;
    }
    if (tid < 8) sAug[1024 + tid] = 0;
    // ---- one-time: x tile (coalesced, block rows are contiguous in x)
    for (int i2 = tid; i2 < ROWS * TAU; i2 += NT) sX[i2] = x[rb0 * TAU + i2];
    if (tid < HID) sWo[tid] = Wo[tid];
    __syncthreads();

    const int w = tid >> 6, L = tid & 63, q = L >> 4, r = L & 15;
    const int lr = w * 16 + r;
    const long gr = rb0 + lr;
    const int Lx8 = L * 8;

    const short* augBase = (q == 0) ? &sAug[(L & 15) * 8] : &sAug[1024];
    const int augStep = (q == 0) ? 128 : 0;

    // ---- state: S_T[i] = H[16T + 4q + i][r]  (16 floats/lane)
    f32x4 S0 = *(const f32x4*)&h0[gr * HID +  0 + 4 * q];
    f32x4 S1 = *(const f32x4*)&h0[gr * HID + 16 + 4 * q];
    f32x4 S2 = *(const f32x4*)&h0[gr * HID + 32 + 4 * q];
    f32x4 S3 = *(const f32x4*)&h0[gr * HID + 48 + 4 * q];

    #pragma unroll 1
    for (int t = 0; t < TAU; ++t) {
        // ---- aug B-frag: [xhi, xhi, xlo, 1, 1, 0, 0, 0] on lanes q==0
        const float xt = sX[lr * TAU + t];
        const unsigned uhi = __builtin_bit_cast(unsigned, xt) & 0xFFFF0000u;
        const float xlo = xt - __builtin_bit_cast(float, uhi);
        unsigned d0 = (uhi >> 16) | uhi;
        unsigned d1 = (__builtin_bit_cast(unsigned, xlo) >> 16) | 0x3F800000u;
        unsigned d2 = 0x00003F80u;
        if (q != 0) { d0 = 0; d1 = 0; d2 = 0; }
        const s16x8 augB = __builtin_bit_cast(s16x8, (u32x4){d0, d1, d2, 0u});

        // ---- B-frags of H (lane-local packs, sigma-aligned)
        s16x8 BH0, BL0, BH1, BL1;
        BUILD_B(S0, S1, S2, S3, BH0, BL0, BH1, BL1)

        // ---- forget gate
        f32x4 Cf0, Cf1, Cf2, Cf3;
        GATE(0, BH0, BL0, BH1, BL1, Cf0, Cf1, Cf2, Cf3)

        f32x4 F0, F1, F2, F3;
        SIG4(F0, Cf0) SIG4(F1, Cf1) SIG4(F2, Cf2) SIG4(F3, Cf3)
        const f32x4 G0 = F0 * S0, G1 = F1 * S1, G2 = F2 * S2, G3 = F3 * S3;
        const f32x4 P0 = S0 - G0, P1 = S1 - G1, P2 = S2 - G2, P3 = S3 - G3;

        // ---- B-frags of G
        s16x8 GH0, GL0, GH1, GL1;
        BUILD_B(G0, G1, G2, G3, GH0, GL0, GH1, GL1)

        // ---- candidate gate
        f32x4 Cc0, Cc1, Cc2, Cc3;
        GATE(1, GH0, GL0, GH1, GL1, Cc0, Cc1, Cc2, Cc3)

        // ---- update: H = P + F * tanh(pre_c)
        UPD4(S0, F0, Cc0, P0) UPD4(S1, F1, Cc1, P1)
        UPD4(S2, F2, Cc2, P2) UPD4(S3, F3, Cc3, P3)
    }

    // ---- output: out[r] = bo + Wo . H ; reduce partial over the 4 q-groups
    const f32x4 wo0 = *(const f32x4*)&sWo[ 0 + 4 * q];
    const f32x4 wo1 = *(const f32x4*)&sWo[16 + 4 * q];
    const f32x4 wo2 = *(const f32x4*)&sWo[32 + 4 * q];
    const f32x4 wo3 = *(const f32x4*)&sWo[48 + 4 * q];
    float acc = 0.0f;
    acc = fmaf(wo0[0], S0[0], acc); acc = fmaf(wo0[1], S0[1], acc);
    acc = fmaf(wo0[2], S0[2], acc); acc = fmaf(wo0[3], S0[3], acc);
    acc = fmaf(wo1[0], S1[0], acc); acc = fmaf(wo1[1], S1[1], acc);
    acc = fmaf(wo1[2], S1[2], acc); acc = fmaf(wo1[3], S1[3], acc);
    acc = fmaf(wo2[0], S2[0], acc); acc = fmaf(wo2[1], S2[1], acc);
    acc = fmaf(wo2[2], S2[2], acc); acc = fmaf(wo2[3], S2[3], acc);
    acc = fmaf(wo3[0], S3[0], acc); acc = fmaf(wo3[1], S3[1], acc);
    acc = fmaf(wo3[2], S3[2], acc); acc = fmaf(wo3[3], S3[3], acc);
    acc += __shfl_xor(acc, 16, 64);
    acc += __shfl_xor(acc, 32, 64);
    if (q == 0) out[gr] = acc + bov[0];
}

extern "C" void kernel_launch(void* const* d_in, const int* in_sizes, int n_in,
                              void* d_out, int out_size, void* d_ws, size_t ws_size,
                              hipStream_t stream) {
    const float* x  = (const float*)d_in[0];
    const float* h0 = (const float*)d_in[1];
    const float* Wf = (const float*)d_in[2];
    const float* bf = (const float*)d_in[3];
    const float* Wc = (const float*)d_in[4];
    const float* bc = (const float*)d_in[5];
    const float* Wo = (const float*)d_in[6];
    const float* bo = (const float*)d_in[7];
    float* out = (float*)d_out;

    dim3 grid(BATCH / ROWS);   // 2048 blocks
    dim3 block(NT);
    hipLaunchKernelGGL(mgu_fwd, grid, block, 0, stream,
                       x, h0, Wf, bf, Wc, bc, Wo, bo, out);
}

// Round 8
// 174.093 us; speedup vs baseline: 3.6322x; 3.6322x over previous
//
#include <hip/hip_runtime.h>

// MGU forward, swapped-orientation split-bf16 MFMA. B=131072, TAU=20, HID=64.
// Block = 64 rows, 4 waves; wave owns 16 rows (r = lane&15), ALL 64 units.
// GEMM computes PRE^T = W * S : A = W (static, LDS, fragment-ordered with
// column permutation sigma), B = state (built IN REGISTERS from the lane's
// own previous D-fragment values -- sigma makes the B-frag slot map lane-local:
//   sigma(32s + 8q + i) = 16*(2s + (i>>2)) + 4q + (i&3)
// so slot i' of kstep s at lane (q,r) = S_{T=2s+(i'>>2)}[i'&3], which is this
// lane's D/epilogue register). Zero cross-lane ops, zero LDS writes, zero
// bank conflicts in the recurrence.
// Bias + x-term: one aug-MFMA per tile/gate, A-slots [fxhi,fxlo,fxhi,fbhi,fblo],
// B-slots [xhi,xhi,xlo,1,1] (lanes q>0 read a zero chunk) -> full precision.
// 3-term split everywhere: hi*hi + lo*hi + hi*lo (drop lo*lo ~2^-17).
//
// CRITICAL (R7 post-mortem): this toolchain's empirical VGPR cap is
// 256 / launch_bounds_arg2  (W=2 -> 128, W=3 -> 84, W=4 -> 64; verified on
// rounds R1/R6/R2-R4-R7 respectively). This kernel has ~100 live VGPRs, so
// W=2 is REQUIRED; W=4 spilled ~40 regs -> 2.4 GB scratch traffic -> 632us.
// Occupancy is unchanged by W: LDS 39.5KB -> 4 blocks/CU and 128 VGPR ->
// 16 waves/CU, both 50%.
//
// Fragment maps (m89-verified, R5/R6-validated end-to-end):
//   A: lane L holds A[m=L&15][k=(L>>4)*8+i] ; B: lane L holds B[k=(L>>4)*8+i][n=L&15]
//   C/D: lane L reg i holds D[m=(L>>4)*4+i][n=L&15]

constexpr int BATCH = 131072;
constexpr int TAU   = 20;
constexpr int HID   = 64;
constexpr int FAN   = 65;
constexpr int NT    = 256;
constexpr int ROWS  = 64;

typedef float    f32x4 __attribute__((ext_vector_type(4)));
typedef short    s16x8 __attribute__((ext_vector_type(8)));
typedef unsigned u32x4 __attribute__((ext_vector_type(4)));

static __device__ __forceinline__ short bf16_rne(float f) {
    unsigned u = __builtin_bit_cast(unsigned, f);
    return (short)((u + 0x7FFFu + ((u >> 16) & 1u)) >> 16);
}
static __device__ __forceinline__ float bf16_up(short s) {
    return __builtin_bit_cast(float, ((unsigned)(unsigned short)s) << 16);
}
static __device__ __forceinline__ float fast_sigmoid(float a) {
    return __builtin_amdgcn_rcpf(1.0f + __expf(-a));
}
static __device__ __forceinline__ float fast_tanh(float a) {
    return 1.0f - 2.0f * __builtin_amdgcn_rcpf(1.0f + __expf(2.0f * a));
}
// pack trunc-bf16(a) into low short, trunc-bf16(b) into high short
static __device__ __forceinline__ unsigned pk2(float a, float b) {
    return (__builtin_bit_cast(unsigned, a) >> 16) |
           (__builtin_bit_cast(unsigned, b) & 0xFFFF0000u);
}
static __device__ __forceinline__ float trunc_hi(float v) {
    return __builtin_bit_cast(float, __builtin_bit_cast(unsigned, v) & 0xFFFF0000u);
}

#define MFMA(A, B, C) __builtin_amdgcn_mfma_f32_16x16x32_bf16((A), (B), (C), 0, 0, 0)

// W fragment chunk base (shorts): (g*8 + T*2 + s)*1024 + p*512 + L*8
#define WOFF(g, T, s) (((g) * 8 + (T) * 2 + (s)) * 1024)

// build hi/lo B-frags for both ksteps from state quads (all lane-local)
#define BUILD_B(SA, SB, SC, SD, BH0v, BL0v, BH1v, BL1v) { \
    const float lA0 = SA[0] - trunc_hi(SA[0]), lA1 = SA[1] - trunc_hi(SA[1]); \
    const float lA2 = SA[2] - trunc_hi(SA[2]), lA3 = SA[3] - trunc_hi(SA[3]); \
    const float lB0 = SB[0] - trunc_hi(SB[0]), lB1 = SB[1] - trunc_hi(SB[1]); \
    const float lB2 = SB[2] - trunc_hi(SB[2]), lB3 = SB[3] - trunc_hi(SB[3]); \
    const float lC0 = SC[0] - trunc_hi(SC[0]), lC1 = SC[1] - trunc_hi(SC[1]); \
    const float lC2 = SC[2] - trunc_hi(SC[2]), lC3 = SC[3] - trunc_hi(SC[3]); \
    const float lD0 = SD[0] - trunc_hi(SD[0]), lD1 = SD[1] - trunc_hi(SD[1]); \
    const float lD2 = SD[2] - trunc_hi(SD[2]), lD3 = SD[3] - trunc_hi(SD[3]); \
    BH0v = __builtin_bit_cast(s16x8, (u32x4){pk2(SA[0],SA[1]), pk2(SA[2],SA[3]), pk2(SB[0],SB[1]), pk2(SB[2],SB[3])}); \
    BL0v = __builtin_bit_cast(s16x8, (u32x4){pk2(lA0,lA1),     pk2(lA2,lA3),     pk2(lB0,lB1),     pk2(lB2,lB3)}); \
    BH1v = __builtin_bit_cast(s16x8, (u32x4){pk2(SC[0],SC[1]), pk2(SC[2],SC[3]), pk2(SD[0],SD[1]), pk2(SD[2],SD[3])}); \
    BL1v = __builtin_bit_cast(s16x8, (u32x4){pk2(lC0,lC1),     pk2(lC2,lC3),     pk2(lD0,lD1),     pk2(lD2,lD3)}); }

// 3-term split accumulation for one (tile, kstep)
#define KMFMA(g, T, s, BH, BL, C) { \
    const s16x8 ah_ = *(const s16x8*)&sW[WOFF(g, T, s) + Lx8]; \
    const s16x8 al_ = *(const s16x8*)&sW[WOFF(g, T, s) + 512 + Lx8]; \
    C = MFMA(ah_, BH, C); C = MFMA(al_, BH, C); C = MFMA(ah_, BL, C); }

// full gate: aug init + 2 ksteps x 4 tiles
#define GATE(g, BH0v, BL0v, BH1v, BL1v, C0, C1, C2, C3) { \
    const f32x4 z_ = {0.f, 0.f, 0.f, 0.f}; \
    C0 = MFMA(*(const s16x8*)&augBase[((g) * 4 + 0) * augStep], augB, z_); \
    C1 = MFMA(*(const s16x8*)&augBase[((g) * 4 + 1) * augStep], augB, z_); \
    C2 = MFMA(*(const s16x8*)&augBase[((g) * 4 + 2) * augStep], augB, z_); \
    C3 = MFMA(*(const s16x8*)&augBase[((g) * 4 + 3) * augStep], augB, z_); \
    KMFMA(g, 0, 0, BH0v, BL0v, C0) KMFMA(g, 1, 0, BH0v, BL0v, C1) \
    KMFMA(g, 2, 0, BH0v, BL0v, C2) KMFMA(g, 3, 0, BH0v, BL0v, C3) \
    KMFMA(g, 0, 1, BH1v, BL1v, C0) KMFMA(g, 1, 1, BH1v, BL1v, C1) \
    KMFMA(g, 2, 1, BH1v, BL1v, C2) KMFMA(g, 3, 1, BH1v, BL1v, C3) }

#define SIG4(F, C) { F[0] = fast_sigmoid(C[0]); F[1] = fast_sigmoid(C[1]); \
                     F[2] = fast_sigmoid(C[2]); F[3] = fast_sigmoid(C[3]); }
#define UPD4(S, F, C, P) { S[0] = fmaf(F[0], fast_tanh(C[0]), P[0]); \
                           S[1] = fmaf(F[1], fast_tanh(C[1]), P[1]); \
                           S[2] = fmaf(F[2], fast_tanh(C[2]), P[2]); \
                           S[3] = fmaf(F[3], fast_tanh(C[3]), P[3]); }

__global__ __launch_bounds__(NT, 2) void mgu_fwd(
    const float* __restrict__ x,    // [B, TAU]
    const float* __restrict__ h0,   // [B, HID]
    const float* __restrict__ Wf,   // [HID, FAN]
    const float* __restrict__ bfv,  // [HID]
    const float* __restrict__ Wc,   // [HID, FAN]
    const float* __restrict__ bcv,  // [HID]
    const float* __restrict__ Wo,   // [1, HID]
    const float* __restrict__ bov,  // [1]
    float* __restrict__ out)        // [B, 1]
{
    __shared__ short sW[16384];        // W frags: (g*8+T*2+s)*1024 + p*512 + L*8 + i
    __shared__ short sAug[1032];       // aug frags (g*4+T)*128 + m*8 + i ; [1024..1031]=0
    __shared__ float sX[ROWS * TAU];   // x tile, [local row][t]
    __shared__ float sWo[HID];

    const int tid = threadIdx.x;
    const long rb0 = (long)blockIdx.x * ROWS;

    // ---- one-time: W -> sigma-permuted, fragment-ordered hi/lo planes
    for (int idx = tid; idx < 8192; idx += NT) {
        const int i = idx & 7, Li = (idx >> 3) & 63, s = (idx >> 9) & 1,
                  T = (idx >> 10) & 3, g = (idx >> 12) & 1;
        const int u = 16 * (2 * s + (i >> 2)) + 4 * (Li >> 4) + (i & 3); // sigma
        const float* Wg = g ? Wc : Wf;
        const float wv = Wg[(16 * T + (Li & 15)) * FAN + 1 + u];
        const short hi = bf16_rne(wv);
        const int base = (g * 8 + T * 2 + s) * 1024 + Li * 8 + i;
        sW[base] = hi;
        sW[base + 512] = bf16_rne(wv - bf16_up(hi));
    }
    // ---- one-time: aug A-frags (bias + x-column), lanes m=0..15 only
    for (int idx = tid; idx < 128; idx += NT) {
        const int m = idx & 15, T = (idx >> 4) & 3, g = (idx >> 6) & 1;
        const float* Wg = g ? Wc : Wf;
        const float* bg = g ? bcv : bfv;
        const float fx = Wg[(16 * T + m) * FAN];
        const float fb = bg[16 * T + m];
        const short fxh = bf16_rne(fx), fbh = bf16_rne(fb);
        short* c = &sAug[(g * 4 + T) * 128 + m * 8];
        c[0] = fxh; c[1] = bf16_rne(fx - bf16_up(fxh)); c[2] = fxh;
        c[3] = fbh; c[4] = bf16_rne(fb - bf16_up(fbh));
        c[5] = 0; c[6] = 0; c[7] = 0;
    }
    if (tid < 8) sAug[1024 + tid] = 0;
    // ---- one-time: x tile (coalesced, block rows are contiguous in x)
    for (int i2 = tid; i2 < ROWS * TAU; i2 += NT) sX[i2] = x[rb0 * TAU + i2];
    if (tid < HID) sWo[tid] = Wo[tid];
    __syncthreads();

    const int w = tid >> 6, L = tid & 63, q = L >> 4, r = L & 15;
    const int lr = w * 16 + r;
    const long gr = rb0 + lr;
    const int Lx8 = L * 8;

    const short* augBase = (q == 0) ? &sAug[(L & 15) * 8] : &sAug[1024];
    const int augStep = (q == 0) ? 128 : 0;

    // ---- state: S_T[i] = H[16T + 4q + i][r]  (16 floats/lane)
    f32x4 S0 = *(const f32x4*)&h0[gr * HID +  0 + 4 * q];
    f32x4 S1 = *(const f32x4*)&h0[gr * HID + 16 + 4 * q];
    f32x4 S2 = *(const f32x4*)&h0[gr * HID + 32 + 4 * q];
    f32x4 S3 = *(const f32x4*)&h0[gr * HID + 48 + 4 * q];

    #pragma unroll 1
    for (int t = 0; t < TAU; ++t) {
        // ---- aug B-frag: [xhi, xhi, xlo, 1, 1, 0, 0, 0] on lanes q==0
        const float xt = sX[lr * TAU + t];
        const unsigned uhi = __builtin_bit_cast(unsigned, xt) & 0xFFFF0000u;
        const float xlo = xt - __builtin_bit_cast(float, uhi);
        unsigned d0 = (uhi >> 16) | uhi;
        unsigned d1 = (__builtin_bit_cast(unsigned, xlo) >> 16) | 0x3F800000u;
        unsigned d2 = 0x00003F80u;
        if (q != 0) { d0 = 0; d1 = 0; d2 = 0; }
        const s16x8 augB = __builtin_bit_cast(s16x8, (u32x4){d0, d1, d2, 0u});

        // ---- B-frags of H (lane-local packs, sigma-aligned)
        s16x8 BH0, BL0, BH1, BL1;
        BUILD_B(S0, S1, S2, S3, BH0, BL0, BH1, BL1)

        // ---- forget gate
        f32x4 Cf0, Cf1, Cf2, Cf3;
        GATE(0, BH0, BL0, BH1, BL1, Cf0, Cf1, Cf2, Cf3)

        f32x4 F0, F1, F2, F3;
        SIG4(F0, Cf0) SIG4(F1, Cf1) SIG4(F2, Cf2) SIG4(F3, Cf3)
        const f32x4 G0 = F0 * S0, G1 = F1 * S1, G2 = F2 * S2, G3 = F3 * S3;
        const f32x4 P0 = S0 - G0, P1 = S1 - G1, P2 = S2 - G2, P3 = S3 - G3;

        // ---- B-frags of G
        s16x8 GH0, GL0, GH1, GL1;
        BUILD_B(G0, G1, G2, G3, GH0, GL0, GH1, GL1)

        // ---- candidate gate
        f32x4 Cc0, Cc1, Cc2, Cc3;
        GATE(1, GH0, GL0, GH1, GL1, Cc0, Cc1, Cc2, Cc3)

        // ---- update: H = P + F * tanh(pre_c)
        UPD4(S0, F0, Cc0, P0) UPD4(S1, F1, Cc1, P1)
        UPD4(S2, F2, Cc2, P2) UPD4(S3, F3, Cc3, P3)
    }

    // ---- output: out[r] = bo + Wo . H ; reduce partial over the 4 q-groups
    const f32x4 wo0 = *(const f32x4*)&sWo[ 0 + 4 * q];
    const f32x4 wo1 = *(const f32x4*)&sWo[16 + 4 * q];
    const f32x4 wo2 = *(const f32x4*)&sWo[32 + 4 * q];
    const f32x4 wo3 = *(const f32x4*)&sWo[48 + 4 * q];
    float acc = 0.0f;
    acc = fmaf(wo0[0], S0[0], acc); acc = fmaf(wo0[1], S0[1], acc);
    acc = fmaf(wo0[2], S0[2], acc); acc = fmaf(wo0[3], S0[3], acc);
    acc = fmaf(wo1[0], S1[0], acc); acc = fmaf(wo1[1], S1[1], acc);
    acc = fmaf(wo1[2], S1[2], acc); acc = fmaf(wo1[3], S1[3], acc);
    acc = fmaf(wo2[0], S2[0], acc); acc = fmaf(wo2[1], S2[1], acc);
    acc = fmaf(wo2[2], S2[2], acc); acc = fmaf(wo2[3], S2[3], acc);
    acc = fmaf(wo3[0], S3[0], acc); acc = fmaf(wo3[1], S3[1], acc);
    acc = fmaf(wo3[2], S3[2], acc); acc = fmaf(wo3[3], S3[3], acc);
    acc += __shfl_xor(acc, 16, 64);
    acc += __shfl_xor(acc, 32, 64);
    if (q == 0) out[gr] = acc + bov[0];
}

extern "C" void kernel_launch(void* const* d_in, const int* in_sizes, int n_in,
                              void* d_out, int out_size, void* d_ws, size_t ws_size,
                              hipStream_t stream) {
    const float* x  = (const float*)d_in[0];
    const float* h0 = (const float*)d_in[1];
    const float* Wf = (const float*)d_in[2];
    const float* bf = (const float*)d_in[3];
    const float* Wc = (const float*)d_in[4];
    const float* bc = (const float*)d_in[5];
    const float* Wo = (const float*)d_in[6];
    const float* bo = (const float*)d_in[7];
    float* out = (float*)d_out;

    dim3 grid(BATCH / ROWS);   // 2048 blocks
    dim3 block(NT);
    hipLaunchKernelGGL(mgu_fwd, grid, block, 0, stream,
                       x, h0, Wf, bf, Wc, bc, Wo, bo, out);
}

// Round 9
// 171.620 us; speedup vs baseline: 3.6845x; 1.0144x over previous
//
#include <hip/hip_runtime.h>

// MGU forward, swapped-orientation split-bf16 MFMA. B=131072, TAU=20, HID=64.
// Block = 128 rows, 8 waves; wave owns 16 rows (r = lane&15), ALL 64 units.
// (NT=512 so the 32KB W-fragment LDS is shared by 8 waves -> 16 waves/CU.)
// GEMM computes PRE^T = W * S : A = W (static, LDS, fragment-ordered with
// column permutation sigma), B = state (built IN REGISTERS from the lane's
// own previous D-fragment values -- sigma makes the B-frag slot map lane-local:
//   sigma(32s + 8q + i) = 16*(2s + (i>>2)) + 4q + (i&3)
// Zero cross-lane ops, zero LDS writes, zero bank conflicts in the recurrence.
// Bias + x-term: one aug-MFMA per tile/gate, A-slots [fxhi,fxlo,fxhi,fbhi,fblo],
// B-slots [xhi,xhi,xlo,1,1]. 3-term split: hi*hi + lo*hi + hi*lo.
//
// EXP2-DOMAIN WEIGHTS (R9): Wf/bf/fx are pre-scaled by -log2(e) and Wc/bc/cx
// by +2*log2(e) at staging, so activations use raw v_exp_f32 (exp2) with no
// per-element multiply:  F = 1/(1+exp2(Cf)),  tanh = 1 - 2/(1+exp2(Cc)).
// PAIRED RCP: 1/d0 = d1*rcp(d0*d1), 1/d1 = d0*rcp(d0*d1) -> halves v_rcp
// count. Saturation: if d0*d1 -> inf, rcp -> 0 and both results hit their
// correct limits (F->0, tanh->1). |pre| <= ~12 for this data; no overflow.
//
// CRITICAL (R7 post-mortem): empirical VGPR cap = 256 / launch_bounds_arg2
// (W=2 -> 128, W=3 -> 84, W=4 -> 64; verified R1/R6/R7). ~100 live VGPRs
// here => W=2 REQUIRED. Runtime residency: VGPR 128 -> 16 waves/CU -> 2
// blocks of 8 waves (LDS 2x45.3KB = 90.6KB <= 160KB OK).
//
// Fragment maps (m89-verified, R5/R6/R8-validated end-to-end):
//   A: lane L holds A[m=L&15][k=(L>>4)*8+i] ; B: lane L holds B[k=(L>>4)*8+i][n=L&15]
//   C/D: lane L reg i holds D[m=(L>>4)*4+i][n=L&15]

constexpr int BATCH = 131072;
constexpr int TAU   = 20;
constexpr int HID   = 64;
constexpr int FAN   = 65;
constexpr int NT    = 512;
constexpr int ROWS  = 128;

typedef float    f32x4 __attribute__((ext_vector_type(4)));
typedef short    s16x8 __attribute__((ext_vector_type(8)));
typedef unsigned u32x4 __attribute__((ext_vector_type(4)));

static constexpr float LOG2E = 1.4426950408889634f;

static __device__ __forceinline__ short bf16_rne(float f) {
    unsigned u = __builtin_bit_cast(unsigned, f);
    return (short)((u + 0x7FFFu + ((u >> 16) & 1u)) >> 16);
}
static __device__ __forceinline__ float bf16_up(short s) {
    return __builtin_bit_cast(float, ((unsigned)(unsigned short)s) << 16);
}
// pack trunc-bf16(a) into low short, trunc-bf16(b) into high short
static __device__ __forceinline__ unsigned pk2(float a, float b) {
    return (__builtin_bit_cast(unsigned, a) >> 16) |
           (__builtin_bit_cast(unsigned, b) & 0xFFFF0000u);
}
static __device__ __forceinline__ float trunc_hi(float v) {
    return __builtin_bit_cast(float, __builtin_bit_cast(unsigned, v) & 0xFFFF0000u);
}

#define MFMA(A, B, C) __builtin_amdgcn_mfma_f32_16x16x32_bf16((A), (B), (C), 0, 0, 0)

// W fragment chunk base (shorts): (g*8 + T*2 + s)*1024 + p*512 + L*8
#define WOFF(g, T, s) (((g) * 8 + (T) * 2 + (s)) * 1024)

// build hi/lo B-frags for both ksteps from state quads (all lane-local)
#define BUILD_B(SA, SB, SC, SD, BH0v, BL0v, BH1v, BL1v) { \
    const float lA0 = SA[0] - trunc_hi(SA[0]), lA1 = SA[1] - trunc_hi(SA[1]); \
    const float lA2 = SA[2] - trunc_hi(SA[2]), lA3 = SA[3] - trunc_hi(SA[3]); \
    const float lB0 = SB[0] - trunc_hi(SB[0]), lB1 = SB[1] - trunc_hi(SB[1]); \
    const float lB2 = SB[2] - trunc_hi(SB[2]), lB3 = SB[3] - trunc_hi(SB[3]); \
    const float lC0 = SC[0] - trunc_hi(SC[0]), lC1 = SC[1] - trunc_hi(SC[1]); \
    const float lC2 = SC[2] - trunc_hi(SC[2]), lC3 = SC[3] - trunc_hi(SC[3]); \
    const float lD0 = SD[0] - trunc_hi(SD[0]), lD1 = SD[1] - trunc_hi(SD[1]); \
    const float lD2 = SD[2] - trunc_hi(SD[2]), lD3 = SD[3] - trunc_hi(SD[3]); \
    BH0v = __builtin_bit_cast(s16x8, (u32x4){pk2(SA[0],SA[1]), pk2(SA[2],SA[3]), pk2(SB[0],SB[1]), pk2(SB[2],SB[3])}); \
    BL0v = __builtin_bit_cast(s16x8, (u32x4){pk2(lA0,lA1),     pk2(lA2,lA3),     pk2(lB0,lB1),     pk2(lB2,lB3)}); \
    BH1v = __builtin_bit_cast(s16x8, (u32x4){pk2(SC[0],SC[1]), pk2(SC[2],SC[3]), pk2(SD[0],SD[1]), pk2(SD[2],SD[3])}); \
    BL1v = __builtin_bit_cast(s16x8, (u32x4){pk2(lC0,lC1),     pk2(lC2,lC3),     pk2(lD0,lD1),     pk2(lD2,lD3)}); }

// 3-term split accumulation for one (tile, kstep)
#define KMFMA(g, T, s, BH, BL, C) { \
    const s16x8 ah_ = *(const s16x8*)&sW[WOFF(g, T, s) + Lx8]; \
    const s16x8 al_ = *(const s16x8*)&sW[WOFF(g, T, s) + 512 + Lx8]; \
    C = MFMA(ah_, BH, C); C = MFMA(al_, BH, C); C = MFMA(ah_, BL, C); }

// full gate: aug init + 2 ksteps x 4 tiles
#define GATE(g, BH0v, BL0v, BH1v, BL1v, C0, C1, C2, C3) { \
    const f32x4 z_ = {0.f, 0.f, 0.f, 0.f}; \
    C0 = MFMA(*(const s16x8*)&augBase[((g) * 4 + 0) * augStep], augB, z_); \
    C1 = MFMA(*(const s16x8*)&augBase[((g) * 4 + 1) * augStep], augB, z_); \
    C2 = MFMA(*(const s16x8*)&augBase[((g) * 4 + 2) * augStep], augB, z_); \
    C3 = MFMA(*(const s16x8*)&augBase[((g) * 4 + 3) * augStep], augB, z_); \
    KMFMA(g, 0, 0, BH0v, BL0v, C0) KMFMA(g, 1, 0, BH0v, BL0v, C1) \
    KMFMA(g, 2, 0, BH0v, BL0v, C2) KMFMA(g, 3, 0, BH0v, BL0v, C3) \
    KMFMA(g, 0, 1, BH1v, BL1v, C0) KMFMA(g, 1, 1, BH1v, BL1v, C1) \
    KMFMA(g, 2, 1, BH1v, BL1v, C2) KMFMA(g, 3, 1, BH1v, BL1v, C3) }

// F = 1/(1 + exp2(C)) per element; paired rcp (2 rcp per 4 elems)
#define SIG4(F, C) { \
    const float e0_ = __builtin_amdgcn_exp2f(C[0]); \
    const float e1_ = __builtin_amdgcn_exp2f(C[1]); \
    const float e2_ = __builtin_amdgcn_exp2f(C[2]); \
    const float e3_ = __builtin_amdgcn_exp2f(C[3]); \
    const float d0_ = 1.0f + e0_, d1_ = 1.0f + e1_; \
    const float d2_ = 1.0f + e2_, d3_ = 1.0f + e3_; \
    const float i01_ = __builtin_amdgcn_rcpf(d0_ * d1_); \
    const float i23_ = __builtin_amdgcn_rcpf(d2_ * d3_); \
    F[0] = d1_ * i01_; F[1] = d0_ * i01_; \
    F[2] = d3_ * i23_; F[3] = d2_ * i23_; }

// S = P + F * tanh; tanh = 1 - 2/(1 + exp2(C)); paired rcp
#define UPD4(S, F, C, P) { \
    const float e0_ = __builtin_amdgcn_exp2f(C[0]); \
    const float e1_ = __builtin_amdgcn_exp2f(C[1]); \
    const float e2_ = __builtin_amdgcn_exp2f(C[2]); \
    const float e3_ = __builtin_amdgcn_exp2f(C[3]); \
    const float d0_ = 1.0f + e0_, d1_ = 1.0f + e1_; \
    const float d2_ = 1.0f + e2_, d3_ = 1.0f + e3_; \
    const float i01_ = __builtin_amdgcn_rcpf(d0_ * d1_); \
    const float i23_ = __builtin_amdgcn_rcpf(d2_ * d3_); \
    const float t0_ = fmaf(-2.0f * d1_, i01_, 1.0f); \
    const float t1_ = fmaf(-2.0f * d0_, i01_, 1.0f); \
    const float t2_ = fmaf(-2.0f * d3_, i23_, 1.0f); \
    const float t3_ = fmaf(-2.0f * d2_, i23_, 1.0f); \
    S[0] = fmaf(F[0], t0_, P[0]); S[1] = fmaf(F[1], t1_, P[1]); \
    S[2] = fmaf(F[2], t2_, P[2]); S[3] = fmaf(F[3], t3_, P[3]); }

__global__ __launch_bounds__(NT, 2) void mgu_fwd(
    const float* __restrict__ x,    // [B, TAU]
    const float* __restrict__ h0,   // [B, HID]
    const float* __restrict__ Wf,   // [HID, FAN]
    const float* __restrict__ bfv,  // [HID]
    const float* __restrict__ Wc,   // [HID, FAN]
    const float* __restrict__ bcv,  // [HID]
    const float* __restrict__ Wo,   // [1, HID]
    const float* __restrict__ bov,  // [1]
    float* __restrict__ out)        // [B, 1]
{
    __shared__ short sW[16384];        // W frags: (g*8+T*2+s)*1024 + p*512 + L*8 + i
    __shared__ short sAug[1032];       // aug frags (g*4+T)*128 + m*8 + i ; [1024..1031]=0
    __shared__ float sX[ROWS * TAU];   // x tile, [local row][t]
    __shared__ float sWo[HID];

    const int tid = threadIdx.x;
    const long rb0 = (long)blockIdx.x * ROWS;

    // ---- one-time: W -> sigma-permuted, fragment-ordered hi/lo planes,
    //      pre-scaled into exp2 domain (forget: -log2e ; candidate: +2log2e)
    for (int idx = tid; idx < 8192; idx += NT) {
        const int i = idx & 7, Li = (idx >> 3) & 63, s = (idx >> 9) & 1,
                  T = (idx >> 10) & 3, g = (idx >> 12) & 1;
        const int u = 16 * (2 * s + (i >> 2)) + 4 * (Li >> 4) + (i & 3); // sigma
        const float* Wg = g ? Wc : Wf;
        const float sc = g ? (2.0f * LOG2E) : (-LOG2E);
        const float wv = sc * Wg[(16 * T + (Li & 15)) * FAN + 1 + u];
        const short hi = bf16_rne(wv);
        const int base = (g * 8 + T * 2 + s) * 1024 + Li * 8 + i;
        sW[base] = hi;
        sW[base + 512] = bf16_rne(wv - bf16_up(hi));
    }
    // ---- one-time: aug A-frags (bias + x-column), scaled identically
    for (int idx = tid; idx < 128; idx += NT) {
        const int m = idx & 15, T = (idx >> 4) & 3, g = (idx >> 6) & 1;
        const float* Wg = g ? Wc : Wf;
        const float* bg = g ? bcv : bfv;
        const float sc = g ? (2.0f * LOG2E) : (-LOG2E);
        const float fx = sc * Wg[(16 * T + m) * FAN];
        const float fb = sc * bg[16 * T + m];
        const short fxh = bf16_rne(fx), fbh = bf16_rne(fb);
        short* c = &sAug[(g * 4 + T) * 128 + m * 8];
        c[0] = fxh; c[1] = bf16_rne(fx - bf16_up(fxh)); c[2] = fxh;
        c[3] = fbh; c[4] = bf16_rne(fb - bf16_up(fbh));
        c[5] = 0; c[6] = 0; c[7] = 0;
    }
    if (tid < 8) sAug[1024 + tid] = 0;
    // ---- one-time: x tile (coalesced, block rows are contiguous in x)
    for (int i2 = tid; i2 < ROWS * TAU; i2 += NT) sX[i2] = x[rb0 * TAU + i2];
    if (tid < HID) sWo[tid] = Wo[tid];
    __syncthreads();

    const int w = tid >> 6, L = tid & 63, q = L >> 4, r = L & 15;
    const int lr = w * 16 + r;
    const long gr = rb0 + lr;
    const int Lx8 = L * 8;

    const short* augBase = (q == 0) ? &sAug[(L & 15) * 8] : &sAug[1024];
    const int augStep = (q == 0) ? 128 : 0;

    // ---- state: S_T[i] = H[16T + 4q + i][r]  (16 floats/lane)
    f32x4 S0 = *(const f32x4*)&h0[gr * HID +  0 + 4 * q];
    f32x4 S1 = *(const f32x4*)&h0[gr * HID + 16 + 4 * q];
    f32x4 S2 = *(const f32x4*)&h0[gr * HID + 32 + 4 * q];
    f32x4 S3 = *(const f32x4*)&h0[gr * HID + 48 + 4 * q];

    #pragma unroll 1
    for (int t = 0; t < TAU; ++t) {
        // ---- aug B-frag: [xhi, xhi, xlo, 1, 1, 0, 0, 0] on lanes q==0
        const float xt = sX[lr * TAU + t];
        const unsigned uhi = __builtin_bit_cast(unsigned, xt) & 0xFFFF0000u;
        const float xlo = xt - __builtin_bit_cast(float, uhi);
        unsigned d0 = (uhi >> 16) | uhi;
        unsigned d1 = (__builtin_bit_cast(unsigned, xlo) >> 16) | 0x3F800000u;
        unsigned d2 = 0x00003F80u;
        if (q != 0) { d0 = 0; d1 = 0; d2 = 0; }
        const s16x8 augB = __builtin_bit_cast(s16x8, (u32x4){d0, d1, d2, 0u});

        // ---- B-frags of H (lane-local packs, sigma-aligned)
        s16x8 BH0, BL0, BH1, BL1;
        BUILD_B(S0, S1, S2, S3, BH0, BL0, BH1, BL1)

        // ---- forget gate (exp2 domain: Cf = -pre * log2e)
        f32x4 Cf0, Cf1, Cf2, Cf3;
        GATE(0, BH0, BL0, BH1, BL1, Cf0, Cf1, Cf2, Cf3)

        f32x4 F0, F1, F2, F3;
        SIG4(F0, Cf0) SIG4(F1, Cf1) SIG4(F2, Cf2) SIG4(F3, Cf3)
        const f32x4 G0 = F0 * S0, G1 = F1 * S1, G2 = F2 * S2, G3 = F3 * S3;
        const f32x4 P0 = S0 - G0, P1 = S1 - G1, P2 = S2 - G2, P3 = S3 - G3;

        // ---- B-frags of G
        s16x8 GH0, GL0, GH1, GL1;
        BUILD_B(G0, G1, G2, G3, GH0, GL0, GH1, GL1)

        // ---- candidate gate (exp2 domain: Cc = 2 * pre * log2e)
        f32x4 Cc0, Cc1, Cc2, Cc3;
        GATE(1, GH0, GL0, GH1, GL1, Cc0, Cc1, Cc2, Cc3)

        // ---- update: H = P + F * tanh
        UPD4(S0, F0, Cc0, P0) UPD4(S1, F1, Cc1, P1)
        UPD4(S2, F2, Cc2, P2) UPD4(S3, F3, Cc3, P3)
    }

    // ---- output: out[r] = bo + Wo . H ; reduce partial over the 4 q-groups
    const f32x4 wo0 = *(const f32x4*)&sWo[ 0 + 4 * q];
    const f32x4 wo1 = *(const f32x4*)&sWo[16 + 4 * q];
    const f32x4 wo2 = *(const f32x4*)&sWo[32 + 4 * q];
    const f32x4 wo3 = *(const f32x4*)&sWo[48 + 4 * q];
    float acc = 0.0f;
    acc = fmaf(wo0[0], S0[0], acc); acc = fmaf(wo0[1], S0[1], acc);
    acc = fmaf(wo0[2], S0[2], acc); acc = fmaf(wo0[3], S0[3], acc);
    acc = fmaf(wo1[0], S1[0], acc); acc = fmaf(wo1[1], S1[1], acc);
    acc = fmaf(wo1[2], S1[2], acc); acc = fmaf(wo1[3], S1[3], acc);
    acc = fmaf(wo2[0], S2[0], acc); acc = fmaf(wo2[1], S2[1], acc);
    acc = fmaf(wo2[2], S2[2], acc); acc = fmaf(wo2[3], S2[3], acc);
    acc = fmaf(wo3[0], S3[0], acc); acc = fmaf(wo3[1], S3[1], acc);
    acc = fmaf(wo3[2], S3[2], acc); acc = fmaf(wo3[3], S3[3], acc);
    acc += __shfl_xor(acc, 16, 64);
    acc += __shfl_xor(acc, 32, 64);
    if (q == 0) out[gr] = acc + bov[0];
}

extern "C" void kernel_launch(void* const* d_in, const int* in_sizes, int n_in,
                              void* d_out, int out_size, void* d_ws, size_t ws_size,
                              hipStream_t stream) {
    const float* x  = (const float*)d_in[0];
    const float* h0 = (const float*)d_in[1];
    const float* Wf = (const float*)d_in[2];
    const float* bf = (const float*)d_in[3];
    const float* Wc = (const float*)d_in[4];
    const float* bc = (const float*)d_in[5];
    const float* Wo = (const float*)d_in[6];
    const float* bo = (const float*)d_in[7];
    float* out = (float*)d_out;

    dim3 grid(BATCH / ROWS);   // 1024 blocks, 128 rows each
    dim3 block(NT);
    hipLaunchKernelGGL(mgu_fwd, grid, block, 0, stream,
                       x, h0, Wf, bf, Wc, bc, Wo, bo, out);
}

// Round 10
// 145.171 us; speedup vs baseline: 4.3558x; 1.1822x over previous
//
#include <hip/hip_runtime.h>

// MGU forward, swapped-orientation split-f16 MFMA. B=131072, TAU=20, HID=64.
// Block = 128 rows, 8 waves; wave owns 16 rows (r = lane&15), ALL 64 units.
// GEMM computes PRE^T = W * S with W split into TWO f16 planes:
//   Whi = f16(W), Wlo = f16((W - Whi) * 256)   [scale dodges f16 denormals]
//   PRE = Ch + 2^-8 * Cl, Ch = Whi*S (+aug), Cl = Wlo*S
// State S enters as a SINGLE f16 plane (err ~2^-12; analysis: absmax ~3e-4).
// sigma column permutation keeps B-frag slots lane-local (zero cross-lane ops):
//   sigma(32s + 8q + i) = 16*(2s + (i>>2)) + 4q + (i&3)
// Traffic split across pipes (R9 lesson: LDS pipe was 75% busy at 40 reads/step):
//   LDS:    W-hi planes (16 ds_read_b128/step)
//   GLOBAL: W-lo planes + aug frags (24 loads/step, 18KB shared table in d_ws,
//           built by a pre-kernel on the same stream -> L2-resident, all blocks share)
// Aug (bias + x) full precision, rank-5:
//   A = [fxh, fxlo*2^8, fxh, fbh, fblo*2^8], B = [xh, xh*2^-8, xl, 1, 2^-8]
// exp2-domain weights: forget plane scaled by -log2e, candidate by +2log2e ->
// activations are raw v_exp_f32 + paired rcp (R9 numerics, unchanged).
// Update without P/G live: S = S + F*(tanh - S).
//
// CRITICAL: empirical VGPR cap = 256 / launch_bounds_arg2 (W=2 -> 128; W=3 -> 84;
// W=4 -> 64; verified R1/R6/R7). Live count here ~105 => W=2 REQUIRED.
//
// Fragment maps (m89-verified, R5-R9 validated end-to-end):
//   A: lane L holds A[m=L&15][k=(L>>4)*8+i] ; B: lane L holds B[k=(L>>4)*8+i][n=L&15]
//   C/D: lane L reg i holds D[m=(L>>4)*4+i][n=L&15]

constexpr int BATCH = 131072;
constexpr int TAU   = 20;
constexpr int HID   = 64;
constexpr int FAN   = 65;
constexpr int NT    = 512;
constexpr int ROWS  = 128;

typedef float    f32x4 __attribute__((ext_vector_type(4)));
typedef _Float16 f16x8 __attribute__((ext_vector_type(8)));

static constexpr float LOG2E  = 1.4426950408889634f;
static constexpr float RCP256 = 0.00390625f;

#define MFMAH(A, B, C) __builtin_amdgcn_mfma_f32_16x16x32_f16((A), (B), (C), 0, 0, 0)

// chunk base (in halfs) for (g, T, s): 16 chunks x 512
#define HOFF(g, T, s) ((((g) * 8) + ((T) * 2) + (s)) * 512)

// ---------------- pre-kernel: build lo-plane + aug table in d_ws ----------------
// ws layout (halfs): [0..8191] lo chunks HOFF(g,T,s)+L*8+i
//                    [8192..9215] aug chunks (g*4+T)*128 + m*8 + i
//                    [9216..9223] zero chunk
__global__ void mgu_stage(const float* __restrict__ Wf, const float* __restrict__ bfv,
                          const float* __restrict__ Wc, const float* __restrict__ bcv,
                          _Float16* __restrict__ ws)
{
    const int tid = threadIdx.x;
    for (int idx = tid; idx < 8192; idx += 256) {
        const int i = idx & 7, Li = (idx >> 3) & 63, s = (idx >> 9) & 1,
                  T = (idx >> 10) & 3, g = (idx >> 12) & 1;
        const int u = 16 * (2 * s + (i >> 2)) + 4 * (Li >> 4) + (i & 3); // sigma
        const float* Wg = g ? Wc : Wf;
        const float sc = g ? (2.0f * LOG2E) : (-LOG2E);
        const float wv = sc * Wg[(16 * T + (Li & 15)) * FAN + 1 + u];
        const _Float16 hi = (_Float16)wv;
        ws[HOFF(g, T, s) + (idx & 511)] = (_Float16)((wv - (float)hi) * 256.0f);
    }
    if (tid < 128) {
        const int m = tid & 15, T = (tid >> 4) & 3, g = tid >> 6;
        const float* Wg = g ? Wc : Wf;
        const float* bg = g ? bcv : bfv;
        const float sc = g ? (2.0f * LOG2E) : (-LOG2E);
        const float fx = sc * Wg[(16 * T + m) * FAN];
        const float fb = sc * bg[16 * T + m];
        const _Float16 fxh = (_Float16)fx;
        const _Float16 fbh = (_Float16)fb;
        _Float16* c = &ws[8192 + (g * 4 + T) * 128 + m * 8];
        c[0] = fxh;
        c[1] = (_Float16)((fx - (float)fxh) * 256.0f);
        c[2] = fxh;
        c[3] = fbh;
        c[4] = (_Float16)((fb - (float)fbh) * 256.0f);
        c[5] = (_Float16)0.0f; c[6] = (_Float16)0.0f; c[7] = (_Float16)0.0f;
    }
    if (tid < 8) ws[9216 + tid] = (_Float16)0.0f;
}

// ---------------- main kernel ----------------

// single-plane f16 B-frag from 8 f32 values (2 state quads)
#define BUILD_BH(SA, SB, OUT) { \
    f16x8 b_; \
    b_[0] = (_Float16)SA[0]; b_[1] = (_Float16)SA[1]; \
    b_[2] = (_Float16)SA[2]; b_[3] = (_Float16)SA[3]; \
    b_[4] = (_Float16)SB[0]; b_[5] = (_Float16)SB[1]; \
    b_[6] = (_Float16)SB[2]; b_[7] = (_Float16)SB[3]; \
    OUT = b_; }

// G = F.*S variant (values computed inline, G never lives as f32 state)
#define BUILD_GH(FA, SA, FB, SB, OUT) { \
    f16x8 b_; \
    b_[0] = (_Float16)(FA[0] * SA[0]); b_[1] = (_Float16)(FA[1] * SA[1]); \
    b_[2] = (_Float16)(FA[2] * SA[2]); b_[3] = (_Float16)(FA[3] * SA[3]); \
    b_[4] = (_Float16)(FB[0] * SB[0]); b_[5] = (_Float16)(FB[1] * SB[1]); \
    b_[6] = (_Float16)(FB[2] * SB[2]); b_[7] = (_Float16)(FB[3] * SB[3]); \
    OUT = b_; }

#define LD_HI(g, T, s)  (*(const f16x8*)&sWhi[HOFF(g, T, s) + Lx8])
#define LD_LO(g, T, s)  (*(const f16x8*)(wsLo + HOFF(g, T, s) + Lx8))
#define LD_AUG(g, T)    (*(const f16x8*)(wsAug + (g * 4 + T) * 128 + augSel))

// one gate: 4 aug MFMA into Ch, then 2 ksteps x 4 tiles x {hi->Ch, lo->Cl}
#define GATEF(g, B0, B1, CH0, CH1, CH2, CH3, CL0, CL1, CL2, CL3) { \
    const f32x4 z_ = {0.f, 0.f, 0.f, 0.f}; \
    CH0 = MFMAH(LD_AUG(g, 0), augB, z_); \
    CH1 = MFMAH(LD_AUG(g, 1), augB, z_); \
    CH2 = MFMAH(LD_AUG(g, 2), augB, z_); \
    CH3 = MFMAH(LD_AUG(g, 3), augB, z_); \
    CL0 = z_; CL1 = z_; CL2 = z_; CL3 = z_; \
    CH0 = MFMAH(LD_HI(g, 0, 0), B0, CH0); CL0 = MFMAH(LD_LO(g, 0, 0), B0, CL0); \
    CH1 = MFMAH(LD_HI(g, 1, 0), B0, CH1); CL1 = MFMAH(LD_LO(g, 1, 0), B0, CL1); \
    CH2 = MFMAH(LD_HI(g, 2, 0), B0, CH2); CL2 = MFMAH(LD_LO(g, 2, 0), B0, CL2); \
    CH3 = MFMAH(LD_HI(g, 3, 0), B0, CH3); CL3 = MFMAH(LD_LO(g, 3, 0), B0, CL3); \
    CH0 = MFMAH(LD_HI(g, 0, 1), B1, CH0); CL0 = MFMAH(LD_LO(g, 0, 1), B1, CL0); \
    CH1 = MFMAH(LD_HI(g, 1, 1), B1, CH1); CL1 = MFMAH(LD_LO(g, 1, 1), B1, CL1); \
    CH2 = MFMAH(LD_HI(g, 2, 1), B1, CH2); CL2 = MFMAH(LD_LO(g, 2, 1), B1, CL2); \
    CH3 = MFMAH(LD_HI(g, 3, 1), B1, CH3); CL3 = MFMAH(LD_LO(g, 3, 1), B1, CL3); }

// F = 1/(1 + exp2(Ch + 2^-8 Cl)) ; paired rcp
#define SIGF4(F, CH, CL) { \
    const float e0_ = __builtin_amdgcn_exp2f(fmaf(RCP256, CL[0], CH[0])); \
    const float e1_ = __builtin_amdgcn_exp2f(fmaf(RCP256, CL[1], CH[1])); \
    const float e2_ = __builtin_amdgcn_exp2f(fmaf(RCP256, CL[2], CH[2])); \
    const float e3_ = __builtin_amdgcn_exp2f(fmaf(RCP256, CL[3], CH[3])); \
    const float d0_ = 1.0f + e0_, d1_ = 1.0f + e1_; \
    const float d2_ = 1.0f + e2_, d3_ = 1.0f + e3_; \
    const float i01_ = __builtin_amdgcn_rcpf(d0_ * d1_); \
    const float i23_ = __builtin_amdgcn_rcpf(d2_ * d3_); \
    F[0] = d1_ * i01_; F[1] = d0_ * i01_; \
    F[2] = d3_ * i23_; F[3] = d2_ * i23_; }

// tanh = 1 - 2/(1 + exp2(.)) ; S = S + F * (tanh - S)
#define UPDF4(S, F, CH, CL) { \
    const float e0_ = __builtin_amdgcn_exp2f(fmaf(RCP256, CL[0], CH[0])); \
    const float e1_ = __builtin_amdgcn_exp2f(fmaf(RCP256, CL[1], CH[1])); \
    const float e2_ = __builtin_amdgcn_exp2f(fmaf(RCP256, CL[2], CH[2])); \
    const float e3_ = __builtin_amdgcn_exp2f(fmaf(RCP256, CL[3], CH[3])); \
    const float d0_ = 1.0f + e0_, d1_ = 1.0f + e1_; \
    const float d2_ = 1.0f + e2_, d3_ = 1.0f + e3_; \
    const float j01_ = -2.0f * __builtin_amdgcn_rcpf(d0_ * d1_); \
    const float j23_ = -2.0f * __builtin_amdgcn_rcpf(d2_ * d3_); \
    const float t0_ = fmaf(d1_, j01_, 1.0f); \
    const float t1_ = fmaf(d0_, j01_, 1.0f); \
    const float t2_ = fmaf(d3_, j23_, 1.0f); \
    const float t3_ = fmaf(d2_, j23_, 1.0f); \
    S[0] = fmaf(F[0], t0_ - S[0], S[0]); S[1] = fmaf(F[1], t1_ - S[1], S[1]); \
    S[2] = fmaf(F[2], t2_ - S[2], S[2]); S[3] = fmaf(F[3], t3_ - S[3], S[3]); }

__global__ __launch_bounds__(NT, 2) void mgu_fwd(
    const float* __restrict__ x,    // [B, TAU]
    const float* __restrict__ h0,   // [B, HID]
    const float* __restrict__ Wf,   // [HID, FAN]
    const float* __restrict__ bfv,  // [HID]
    const float* __restrict__ Wc,   // [HID, FAN]
    const float* __restrict__ bcv,  // [HID]
    const float* __restrict__ Wo,   // [1, HID]
    const float* __restrict__ bov,  // [1]
    const _Float16* __restrict__ ws, // staged lo/aug table
    float* __restrict__ out)        // [B, 1]
{
    __shared__ _Float16 sWhi[8192];   // hi planes, 16 chunks x 512
    __shared__ float sX[ROWS * TAU];
    __shared__ float sWo[HID];

    const int tid = threadIdx.x;
    const long rb0 = (long)blockIdx.x * ROWS;

    // ---- one-time: hi planes -> LDS (sigma order, exp2-domain scale)
    for (int idx = tid; idx < 8192; idx += NT) {
        const int i = idx & 7, Li = (idx >> 3) & 63, s = (idx >> 9) & 1,
                  T = (idx >> 10) & 3, g = (idx >> 12) & 1;
        const int u = 16 * (2 * s + (i >> 2)) + 4 * (Li >> 4) + (i & 3); // sigma
        const float* Wg = g ? Wc : Wf;
        const float sc = g ? (2.0f * LOG2E) : (-LOG2E);
        sWhi[HOFF(g, T, s) + (idx & 511)] =
            (_Float16)(sc * Wg[(16 * T + (Li & 15)) * FAN + 1 + u]);
    }
    for (int i2 = tid; i2 < ROWS * TAU; i2 += NT) sX[i2] = x[rb0 * TAU + i2];
    if (tid < HID) sWo[tid] = Wo[tid];
    __syncthreads();

    const int w = tid >> 6, L = tid & 63, q = L >> 4, r = L & 15;
    const int lr = w * 16 + r;
    const long gr = rb0 + lr;
    const int Lx8 = L * 8;

    const _Float16* wsLo  = ws;
    const _Float16* wsAug = ws + 8192;
    const int augSel = (q == 0) ? (r * 8) : 1024;   // zero chunk for q>0

    // ---- state: S_T[i] = H[16T + 4q + i][r]
    f32x4 S0 = *(const f32x4*)&h0[gr * HID +  0 + 4 * q];
    f32x4 S1 = *(const f32x4*)&h0[gr * HID + 16 + 4 * q];
    f32x4 S2 = *(const f32x4*)&h0[gr * HID + 32 + 4 * q];
    f32x4 S3 = *(const f32x4*)&h0[gr * HID + 48 + 4 * q];

    #pragma unroll 1
    for (int t = 0; t < TAU; ++t) {
        // ---- aug B-frag: [xh, xh*2^-8, xl, 1, 2^-8, 0,0,0] on q==0 lanes
        const float xt = sX[lr * TAU + t];
        f16x8 augB;
        {
            const _Float16 xh = (_Float16)xt;
            const float xhf = (float)xh;
            const bool z = (q != 0);
            augB[0] = z ? (_Float16)0.0f : xh;
            augB[1] = z ? (_Float16)0.0f : (_Float16)(xhf * RCP256);
            augB[2] = z ? (_Float16)0.0f : (_Float16)(xt - xhf);
            augB[3] = z ? (_Float16)0.0f : (_Float16)1.0f;
            augB[4] = z ? (_Float16)0.0f : (_Float16)RCP256;
            augB[5] = (_Float16)0.0f; augB[6] = (_Float16)0.0f; augB[7] = (_Float16)0.0f;
        }

        // ---- B-frags of S (single f16 plane, sigma-aligned)
        f16x8 BS0, BS1;
        BUILD_BH(S0, S1, BS0)
        BUILD_BH(S2, S3, BS1)

        // ---- forget gate
        f32x4 Ch0, Ch1, Ch2, Ch3, Cl0, Cl1, Cl2, Cl3;
        __builtin_amdgcn_s_setprio(1);
        GATEF(0, BS0, BS1, Ch0, Ch1, Ch2, Ch3, Cl0, Cl1, Cl2, Cl3)
        __builtin_amdgcn_s_setprio(0);

        f32x4 F0, F1, F2, F3;
        SIGF4(F0, Ch0, Cl0) SIGF4(F1, Ch1, Cl1)
        SIGF4(F2, Ch2, Cl2) SIGF4(F3, Ch3, Cl3)

        // ---- B-frags of G = F.*S (computed inline, not kept live)
        f16x8 BG0, BG1;
        BUILD_GH(F0, S0, F1, S1, BG0)
        BUILD_GH(F2, S2, F3, S3, BG1)

        // ---- candidate gate
        __builtin_amdgcn_s_setprio(1);
        GATEF(1, BG0, BG1, Ch0, Ch1, Ch2, Ch3, Cl0, Cl1, Cl2, Cl3)
        __builtin_amdgcn_s_setprio(0);

        // ---- update: S = S + F * (tanh - S)
        UPDF4(S0, F0, Ch0, Cl0) UPDF4(S1, F1, Ch1, Cl1)
        UPDF4(S2, F2, Ch2, Cl2) UPDF4(S3, F3, Ch3, Cl3)
    }

    // ---- output: out[r] = bo + Wo . H ; reduce over the 4 q-groups
    const f32x4 wo0 = *(const f32x4*)&sWo[ 0 + 4 * q];
    const f32x4 wo1 = *(const f32x4*)&sWo[16 + 4 * q];
    const f32x4 wo2 = *(const f32x4*)&sWo[32 + 4 * q];
    const f32x4 wo3 = *(const f32x4*)&sWo[48 + 4 * q];
    float acc = 0.0f;
    acc = fmaf(wo0[0], S0[0], acc); acc = fmaf(wo0[1], S0[1], acc);
    acc = fmaf(wo0[2], S0[2], acc); acc = fmaf(wo0[3], S0[3], acc);
    acc = fmaf(wo1[0], S1[0], acc); acc = fmaf(wo1[1], S1[1], acc);
    acc = fmaf(wo1[2], S1[2], acc); acc = fmaf(wo1[3], S1[3], acc);
    acc = fmaf(wo2[0], S2[0], acc); acc = fmaf(wo2[1], S2[1], acc);
    acc = fmaf(wo2[2], S2[2], acc); acc = fmaf(wo2[3], S2[3], acc);
    acc = fmaf(wo3[0], S3[0], acc); acc = fmaf(wo3[1], S3[1], acc);
    acc = fmaf(wo3[2], S3[2], acc); acc = fmaf(wo3[3], S3[3], acc);
    acc += __shfl_xor(acc, 16, 64);
    acc += __shfl_xor(acc, 32, 64);
    if (q == 0) out[gr] = acc + bov[0];
}

extern "C" void kernel_launch(void* const* d_in, const int* in_sizes, int n_in,
                              void* d_out, int out_size, void* d_ws, size_t ws_size,
                              hipStream_t stream) {
    const float* x  = (const float*)d_in[0];
    const float* h0 = (const float*)d_in[1];
    const float* Wf = (const float*)d_in[2];
    const float* bf = (const float*)d_in[3];
    const float* Wc = (const float*)d_in[4];
    const float* bc = (const float*)d_in[5];
    const float* Wo = (const float*)d_in[6];
    const float* bo = (const float*)d_in[7];
    float* out = (float*)d_out;
    _Float16* ws = (_Float16*)d_ws;   // needs 9224 halfs = 18.5 KB

    hipLaunchKernelGGL(mgu_stage, dim3(1), dim3(256), 0, stream,
                       Wf, bf, Wc, bc, ws);
    hipLaunchKernelGGL(mgu_fwd, dim3(BATCH / ROWS), dim3(NT), 0, stream,
                       x, h0, Wf, bf, Wc, bc, Wo, bo, (const _Float16*)ws, out);
}

// Round 11
// 141.200 us; speedup vs baseline: 4.4783x; 1.0281x over previous
//
#include <hip/hip_runtime.h>

// MGU forward, swapped-orientation split-f16 MFMA, per-tile-fused schedule.
// B=131072, TAU=20, HID=64. Block = 128 rows, 8 waves; wave owns 16 rows
// (r = lane&15), ALL 64 units. PRE^T = W * S, W in 2 f16 planes:
//   Whi = f16(W), Wlo = f16((W-Whi)*256); PRE = Ch + 2^-8*Cl.
// State enters as a single f16 plane. sigma keeps B-frag slots lane-local:
//   sigma(32s + 8q + i) = 16*(2s + (i>>2)) + 4q + (i&3)
// Pipes: LDS = W-hi (16 ds_read_b128/step); GLOBAL(L2) = W-lo + aug (24/step,
// 20KB table in d_ws from pre-kernel); VALU = activations; MFMA = 40/step.
//
// R11 changes (R10 post-mortem: VALU 87us busy at 56% -> issue bubbles +
// trans-heavy):
//  * per-tile fusion: C-gate aug MFMAs issued at step start; F computed in
//    tile pairs with BG0/kstep0-C MFMAs interleaved between them -> each
//    trans burst has independent MFMA work adjacent (intra-wave ILP).
//  * v_cvt_pkrtz_f16_f32 everywhere (BS/BG/aug): ~24 fewer VALU ops/step.
// Occupancy intentionally unchanged: grid 1024 = 2 clean rounds of 2 blocks/CU
// (16 waves); higher waves/CU only adds tail imbalance at this block size.
//
// CRITICAL: empirical VGPR cap = 256 / launch_bounds_arg2 (W=2 -> 128;
// W=3 -> 84; W=4 -> 64; verified R1/R6/R7). Peak live ~105-110 => W=2.
//
// Fragment maps (m89-verified, R5-R10 validated end-to-end):
//   A: lane L holds A[m=L&15][k=(L>>4)*8+i]; B: lane L holds B[k=(L>>4)*8+i][n=L&15]
//   C/D: lane L reg i holds D[m=(L>>4)*4+i][n=L&15]

constexpr int BATCH = 131072;
constexpr int TAU   = 20;
constexpr int HID   = 64;
constexpr int FAN   = 65;
constexpr int NT    = 512;
constexpr int ROWS  = 128;

typedef float    f32x4 __attribute__((ext_vector_type(4)));
typedef _Float16 f16x8 __attribute__((ext_vector_type(8)));
typedef unsigned u32x4 __attribute__((ext_vector_type(4)));

static constexpr float LOG2E  = 1.4426950408889634f;
static constexpr float RCP256 = 0.00390625f;

static __device__ __forceinline__ unsigned pkrtz(float a, float b) {
    return __builtin_bit_cast(unsigned, __builtin_amdgcn_cvt_pkrtz(a, b));
}
#define PK8(a0,a1,a2,a3,a4,a5,a6,a7) \
    __builtin_bit_cast(f16x8, (u32x4){pkrtz(a0,a1), pkrtz(a2,a3), \
                                      pkrtz(a4,a5), pkrtz(a6,a7)})

#define MFMAH(A, B, C) __builtin_amdgcn_mfma_f32_16x16x32_f16((A), (B), (C), 0, 0, 0)

// chunk base (in halfs) for (g, T, s): 16 chunks x 512
#define HOFF(g, T, s) ((((g) * 8) + ((T) * 2) + (s)) * 512)

// ---------------- pre-kernel: lo-plane + aug table + zero pad in d_ws -------
// ws layout (halfs): [0..8191] lo chunks HOFF(g,T,s)+L*8+i
//                    [8192..9215] aug chunks (g*4+T)*128 + m*8 + i
//                    [9216..10239] zeros (q!=0 aug reads land here)
__global__ void mgu_stage(const float* __restrict__ Wf, const float* __restrict__ bfv,
                          const float* __restrict__ Wc, const float* __restrict__ bcv,
                          _Float16* __restrict__ ws)
{
    const int tid = threadIdx.x;
    for (int idx = tid; idx < 8192; idx += 256) {
        const int i = idx & 7, Li = (idx >> 3) & 63, s = (idx >> 9) & 1,
                  T = (idx >> 10) & 3, g = (idx >> 12) & 1;
        const int u = 16 * (2 * s + (i >> 2)) + 4 * (Li >> 4) + (i & 3); // sigma
        const float* Wg = g ? Wc : Wf;
        const float sc = g ? (2.0f * LOG2E) : (-LOG2E);
        const float wv = sc * Wg[(16 * T + (Li & 15)) * FAN + 1 + u];
        const _Float16 hi = (_Float16)wv;
        ws[HOFF(g, T, s) + (idx & 511)] = (_Float16)((wv - (float)hi) * 256.0f);
    }
    if (tid < 128) {
        const int m = tid & 15, T = (tid >> 4) & 3, g = tid >> 6;
        const float* Wg = g ? Wc : Wf;
        const float* bg = g ? bcv : bfv;
        const float sc = g ? (2.0f * LOG2E) : (-LOG2E);
        const float fx = sc * Wg[(16 * T + m) * FAN];
        const float fb = sc * bg[16 * T + m];
        const _Float16 fxh = (_Float16)fx;
        const _Float16 fbh = (_Float16)fb;
        _Float16* c = &ws[8192 + (g * 4 + T) * 128 + m * 8];
        c[0] = fxh;
        c[1] = (_Float16)((fx - (float)fxh) * 256.0f);
        c[2] = fxh;
        c[3] = fbh;
        c[4] = (_Float16)((fb - (float)fbh) * 256.0f);
        c[5] = (_Float16)0.0f; c[6] = (_Float16)0.0f; c[7] = (_Float16)0.0f;
    }
    for (int idx = tid; idx < 1024; idx += 256) ws[9216 + idx] = (_Float16)0.0f;
}

// ---------------- main kernel ----------------

#define LD_HI(g, T, s)  (*(const f16x8*)&sWhi[HOFF(g, T, s) + Lx8])
#define LD_LO(g, T, s)  (*(const f16x8*)(wsLo + HOFF(g, T, s) + Lx8))
#define LD_AUG(g, T)    (*(const f16x8*)(wsAug + (g * 4 + T) * 128 + augSel))

// F = 1/(1 + exp2(Ch + 2^-8 Cl)); paired rcp
#define SIGF4(F, CH, CL) { \
    const float e0_ = __builtin_amdgcn_exp2f(fmaf(RCP256, CL[0], CH[0])); \
    const float e1_ = __builtin_amdgcn_exp2f(fmaf(RCP256, CL[1], CH[1])); \
    const float e2_ = __builtin_amdgcn_exp2f(fmaf(RCP256, CL[2], CH[2])); \
    const float e3_ = __builtin_amdgcn_exp2f(fmaf(RCP256, CL[3], CH[3])); \
    const float d0_ = 1.0f + e0_, d1_ = 1.0f + e1_; \
    const float d2_ = 1.0f + e2_, d3_ = 1.0f + e3_; \
    const float i01_ = __builtin_amdgcn_rcpf(d0_ * d1_); \
    const float i23_ = __builtin_amdgcn_rcpf(d2_ * d3_); \
    F[0] = d1_ * i01_; F[1] = d0_ * i01_; \
    F[2] = d3_ * i23_; F[3] = d2_ * i23_; }

// tanh = 1 - 2/(1 + exp2(.)); S = S + F * (tanh - S)
#define UPDF4(S, F, CH, CL) { \
    const float e0_ = __builtin_amdgcn_exp2f(fmaf(RCP256, CL[0], CH[0])); \
    const float e1_ = __builtin_amdgcn_exp2f(fmaf(RCP256, CL[1], CH[1])); \
    const float e2_ = __builtin_amdgcn_exp2f(fmaf(RCP256, CL[2], CH[2])); \
    const float e3_ = __builtin_amdgcn_exp2f(fmaf(RCP256, CL[3], CH[3])); \
    const float d0_ = 1.0f + e0_, d1_ = 1.0f + e1_; \
    const float d2_ = 1.0f + e2_, d3_ = 1.0f + e3_; \
    const float j01_ = -2.0f * __builtin_amdgcn_rcpf(d0_ * d1_); \
    const float j23_ = -2.0f * __builtin_amdgcn_rcpf(d2_ * d3_); \
    const float t0_ = fmaf(d1_, j01_, 1.0f); \
    const float t1_ = fmaf(d0_, j01_, 1.0f); \
    const float t2_ = fmaf(d3_, j23_, 1.0f); \
    const float t3_ = fmaf(d2_, j23_, 1.0f); \
    S[0] = fmaf(F[0], t0_ - S[0], S[0]); S[1] = fmaf(F[1], t1_ - S[1], S[1]); \
    S[2] = fmaf(F[2], t2_ - S[2], S[2]); S[3] = fmaf(F[3], t3_ - S[3], S[3]); }

// one forget-gate tile: aug + 2 ksteps (hi+lo) + sigmoid, C-regs local
#define FTILE(T, FT) { \
    f32x4 ch_ = MFMAH(LD_AUG(0, T), augB, z4); \
    f32x4 cl_ = z4; \
    ch_ = MFMAH(LD_HI(0, T, 0), BS0, ch_); cl_ = MFMAH(LD_LO(0, T, 0), BS0, cl_); \
    ch_ = MFMAH(LD_HI(0, T, 1), BS1, ch_); cl_ = MFMAH(LD_LO(0, T, 1), BS1, cl_); \
    SIGF4(FT, ch_, cl_) }

__global__ __launch_bounds__(NT, 2) void mgu_fwd(
    const float* __restrict__ x,    // [B, TAU]
    const float* __restrict__ h0,   // [B, HID]
    const float* __restrict__ Wf,   // [HID, FAN]
    const float* __restrict__ bfv,  // [HID]
    const float* __restrict__ Wc,   // [HID, FAN]
    const float* __restrict__ bcv,  // [HID]
    const float* __restrict__ Wo,   // [1, HID]
    const float* __restrict__ bov,  // [1]
    const _Float16* __restrict__ ws,
    float* __restrict__ out)        // [B, 1]
{
    __shared__ _Float16 sWhi[8192];   // hi planes, 16 chunks x 512
    __shared__ float sX[ROWS * TAU];
    __shared__ float sWo[HID];

    const int tid = threadIdx.x;
    const long rb0 = (long)blockIdx.x * ROWS;

    // ---- one-time: hi planes -> LDS (sigma order, exp2-domain scale)
    for (int idx = tid; idx < 8192; idx += NT) {
        const int i = idx & 7, Li = (idx >> 3) & 63, s = (idx >> 9) & 1,
                  T = (idx >> 10) & 3, g = (idx >> 12) & 1;
        const int u = 16 * (2 * s + (i >> 2)) + 4 * (Li >> 4) + (i & 3); // sigma
        const float* Wg = g ? Wc : Wf;
        const float sc = g ? (2.0f * LOG2E) : (-LOG2E);
        sWhi[HOFF(g, T, s) + (idx & 511)] =
            (_Float16)(sc * Wg[(16 * T + (Li & 15)) * FAN + 1 + u]);
    }
    for (int i2 = tid; i2 < ROWS * TAU; i2 += NT) sX[i2] = x[rb0 * TAU + i2];
    if (tid < HID) sWo[tid] = Wo[tid];
    __syncthreads();

    const int w = tid >> 6, L = tid & 63, q = L >> 4, r = L & 15;
    const int lr = w * 16 + r;
    const long gr = rb0 + lr;
    const int Lx8 = L * 8;

    const _Float16* wsLo  = ws;
    const _Float16* wsAug = ws + 8192;
    const int augSel = (q == 0) ? (r * 8) : 1024;   // q>0 -> zero pad region

    const f32x4 z4 = {0.f, 0.f, 0.f, 0.f};

    // ---- state: S_T[i] = H[16T + 4q + i][r]
    f32x4 S0 = *(const f32x4*)&h0[gr * HID +  0 + 4 * q];
    f32x4 S1 = *(const f32x4*)&h0[gr * HID + 16 + 4 * q];
    f32x4 S2 = *(const f32x4*)&h0[gr * HID + 32 + 4 * q];
    f32x4 S3 = *(const f32x4*)&h0[gr * HID + 48 + 4 * q];

    #pragma unroll 1
    for (int t = 0; t < TAU; ++t) {
        // ---- aug B-frag: [xh, xh*2^-8, xl, 1, 2^-8, 0,0,0] (q==0 lanes)
        const float xt = sX[lr * TAU + t];
        f16x8 augB;
        {
            const _Float16 xh = (_Float16)xt;
            const float xhf = (float)xh;
            unsigned d0 = pkrtz(xhf, xhf * RCP256);
            unsigned d1 = pkrtz(xt - xhf, 1.0f);
            unsigned d2 = pkrtz(RCP256, 0.0f);
            if (q != 0) { d0 = 0; d1 = 0; d2 = 0; }
            augB = __builtin_bit_cast(f16x8, (u32x4){d0, d1, d2, 0u});
        }

        // ---- B-frags of S (single f16 plane, pkrtz)
        const f16x8 BS0 = PK8(S0[0],S0[1],S0[2],S0[3], S1[0],S1[1],S1[2],S1[3]);
        const f16x8 BS1 = PK8(S2[0],S2[1],S2[2],S2[3], S3[0],S3[1],S3[2],S3[3]);

        // ---- candidate-gate aug MFMAs: depend only on x -> issue first
        f32x4 CcH0 = MFMAH(LD_AUG(1, 0), augB, z4);
        f32x4 CcH1 = MFMAH(LD_AUG(1, 1), augB, z4);
        f32x4 CcH2 = MFMAH(LD_AUG(1, 2), augB, z4);
        f32x4 CcH3 = MFMAH(LD_AUG(1, 3), augB, z4);
        f32x4 CcL0 = z4, CcL1 = z4, CcL2 = z4, CcL3 = z4;

        // ---- F tiles 0,1 (their SIGF overlaps C-aug / later MFMAs)
        f32x4 F0, F1, F2, F3;
        FTILE(0, F0)
        FTILE(1, F1)

        // ---- BG0 (units 0..31) ready -> C-gate kstep 0
        const f32x4 G0 = F0 * S0, G1 = F1 * S1;
        const f16x8 BG0 = PK8(G0[0],G0[1],G0[2],G0[3], G1[0],G1[1],G1[2],G1[3]);
        __builtin_amdgcn_s_setprio(1);
        CcH0 = MFMAH(LD_HI(1, 0, 0), BG0, CcH0); CcL0 = MFMAH(LD_LO(1, 0, 0), BG0, CcL0);
        CcH1 = MFMAH(LD_HI(1, 1, 0), BG0, CcH1); CcL1 = MFMAH(LD_LO(1, 1, 0), BG0, CcL1);
        CcH2 = MFMAH(LD_HI(1, 2, 0), BG0, CcH2); CcL2 = MFMAH(LD_LO(1, 2, 0), BG0, CcL2);
        CcH3 = MFMAH(LD_HI(1, 3, 0), BG0, CcH3); CcL3 = MFMAH(LD_LO(1, 3, 0), BG0, CcL3);
        __builtin_amdgcn_s_setprio(0);

        // ---- F tiles 2,3 (SIGF overlaps kstep-0 MFMAs above)
        FTILE(2, F2)
        FTILE(3, F3)

        // ---- BG1 (units 32..63) -> C-gate kstep 1
        const f32x4 G2 = F2 * S2, G3 = F3 * S3;
        const f16x8 BG1 = PK8(G2[0],G2[1],G2[2],G2[3], G3[0],G3[1],G3[2],G3[3]);
        __builtin_amdgcn_s_setprio(1);
        CcH0 = MFMAH(LD_HI(1, 0, 1), BG1, CcH0); CcL0 = MFMAH(LD_LO(1, 0, 1), BG1, CcL0);
        CcH1 = MFMAH(LD_HI(1, 1, 1), BG1, CcH1); CcL1 = MFMAH(LD_LO(1, 1, 1), BG1, CcL1);
        CcH2 = MFMAH(LD_HI(1, 2, 1), BG1, CcH2); CcL2 = MFMAH(LD_LO(1, 2, 1), BG1, CcL2);
        CcH3 = MFMAH(LD_HI(1, 3, 1), BG1, CcH3); CcL3 = MFMAH(LD_LO(1, 3, 1), BG1, CcL3);
        __builtin_amdgcn_s_setprio(0);

        // ---- update: S = S + F * (tanh - S)
        UPDF4(S0, F0, CcH0, CcL0)
        UPDF4(S1, F1, CcH1, CcL1)
        UPDF4(S2, F2, CcH2, CcL2)
        UPDF4(S3, F3, CcH3, CcL3)
    }

    // ---- output: out[r] = bo + Wo . H ; reduce over the 4 q-groups
    const f32x4 wo0 = *(const f32x4*)&sWo[ 0 + 4 * q];
    const f32x4 wo1 = *(const f32x4*)&sWo[16 + 4 * q];
    const f32x4 wo2 = *(const f32x4*)&sWo[32 + 4 * q];
    const f32x4 wo3 = *(const f32x4*)&sWo[48 + 4 * q];
    float acc = 0.0f;
    acc = fmaf(wo0[0], S0[0], acc); acc = fmaf(wo0[1], S0[1], acc);
    acc = fmaf(wo0[2], S0[2], acc); acc = fmaf(wo0[3], S0[3], acc);
    acc = fmaf(wo1[0], S1[0], acc); acc = fmaf(wo1[1], S1[1], acc);
    acc = fmaf(wo1[2], S1[2], acc); acc = fmaf(wo1[3], S1[3], acc);
    acc = fmaf(wo2[0], S2[0], acc); acc = fmaf(wo2[1], S2[1], acc);
    acc = fmaf(wo2[2], S2[2], acc); acc = fmaf(wo2[3], S2[3], acc);
    acc = fmaf(wo3[0], S3[0], acc); acc = fmaf(wo3[1], S3[1], acc);
    acc = fmaf(wo3[2], S3[2], acc); acc = fmaf(wo3[3], S3[3], acc);
    acc += __shfl_xor(acc, 16, 64);
    acc += __shfl_xor(acc, 32, 64);
    if (q == 0) out[gr] = acc + bov[0];
}

extern "C" void kernel_launch(void* const* d_in, const int* in_sizes, int n_in,
                              void* d_out, int out_size, void* d_ws, size_t ws_size,
                              hipStream_t stream) {
    const float* x  = (const float*)d_in[0];
    const float* h0 = (const float*)d_in[1];
    const float* Wf = (const float*)d_in[2];
    const float* bf = (const float*)d_in[3];
    const float* Wc = (const float*)d_in[4];
    const float* bc = (const float*)d_in[5];
    const float* Wo = (const float*)d_in[6];
    const float* bo = (const float*)d_in[7];
    float* out = (float*)d_out;
    _Float16* ws = (_Float16*)d_ws;   // needs 10240 halfs = 20.5 KB

    hipLaunchKernelGGL(mgu_stage, dim3(1), dim3(256), 0, stream,
                       Wf, bf, Wc, bc, ws);
    hipLaunchKernelGGL(mgu_fwd, dim3(BATCH / ROWS), dim3(NT), 0, stream,
                       x, h0, Wf, bf, Wc, bc, Wo, bo, (const _Float16*)ws, out);
}